// Round 1
// baseline (666.506 us; speedup 1.0000x reference)
//
#include <hip/hip_runtime.h>
#include <hip/hip_bf16.h>

// NodeModelBase: per-edge MLP (Linear->LN->ReLU->Linear) + scatter_mean.
// Strategy: bf16 MFMA (16x16x32) in "swapped" orientation D[n][e] = W^T * feat,
// weights register-resident, CSR sort + segmented mean (no 102M fp32 atomics).

typedef __bf16 bf16x8 __attribute__((ext_vector_type(8)));
typedef float f32x4 __attribute__((ext_vector_type(4)));

#define LN_EPS 1e-5f

__device__ __forceinline__ unsigned short bfbits(float f) {
  return __builtin_bit_cast(unsigned short, (__bf16)f);
}
__device__ __forceinline__ float bflo(unsigned int u) { return __uint_as_float(u << 16); }
__device__ __forceinline__ float bfhi(unsigned int u) { return __uint_as_float(u & 0xffff0000u); }

// ---------------------------------------------------------------- histogram
__global__ void hist_kernel(const int* __restrict__ eidx, int* __restrict__ cnt, int E) {
  int e = blockIdx.x * blockDim.x + threadIdx.x;
  if (e < E) atomicAdd(&cnt[eidx[E + e]], 1);
}

// ------------------------------------------------------- exclusive scan (1 WG)
__global__ void scan_kernel(const int* __restrict__ cnt, int* __restrict__ off, int n) {
  __shared__ int wsum[16];
  __shared__ int carry_s;
  const int tid = threadIdx.x;
  const int wv = tid >> 6;
  const int ln = tid & 63;
  if (tid == 0) carry_s = 0;
  __syncthreads();
  for (int base = 0; base < n; base += 4096) {
    int i0 = base + tid * 4;
    int a = (i0 < n) ? cnt[i0] : 0;
    int b = (i0 + 1 < n) ? cnt[i0 + 1] : 0;
    int c = (i0 + 2 < n) ? cnt[i0 + 2] : 0;
    int d = (i0 + 3 < n) ? cnt[i0 + 3] : 0;
    int lsum = a + b + c + d;
    int sc = lsum;
#pragma unroll
    for (int dl = 1; dl < 64; dl <<= 1) {
      int t = __shfl_up(sc, dl);
      if (ln >= dl) sc += t;
    }
    if (ln == 63) wsum[wv] = sc;
    __syncthreads();
    int woff = 0;
#pragma unroll
    for (int w = 0; w < 16; ++w) {
      int t = wsum[w];
      if (w < wv) woff += t;
    }
    int excl = carry_s + woff + sc - lsum;
    if (i0 < n) off[i0] = excl;
    if (i0 + 1 < n) off[i0 + 1] = excl + a;
    if (i0 + 2 < n) off[i0 + 2] = excl + a + b;
    if (i0 + 3 < n) off[i0 + 3] = excl + a + b + c;
    __syncthreads();
    if (tid == 1023) carry_s = carry_s + woff + sc;
    __syncthreads();
  }
}

// ------------------------------------------------------------ bucket scatter
__global__ void scatter_kernel(const int* __restrict__ eidx, const int* __restrict__ off,
                               int* __restrict__ cur, int* __restrict__ perm, int E) {
  int e = blockIdx.x * blockDim.x + threadIdx.x;
  if (e < E) {
    int c = eidx[E + e];
    int p = atomicAdd(&cur[c], 1);
    perm[off[c] + p] = e;
  }
}

// ----------------------------------------------------------------- main MLP
// Per 16-edge tile, per wave:
//   GEMM1: D1[n1][e] = sum_k W1[k][n1] * feat[e][k]   (A = W1^T frags in regs,
//          B = features loaded straight from global as 8-consecutive-k frags)
//   LN over n1 (lane holds 32 vals of ONE edge; 2 shfl_xor finish the stats)
//   LDS round-trip to convert C-layout -> B-operand layout for GEMM2
//   GEMM2: D2[n2][e] = sum_k W2[k][n2] * hrelu[e][k]
//   Epilogue: either coalesced bf16 store of h2[e][:] to ws (two-phase path)
//             or fp32 atomic scatter into out (fallback path).
template <bool ATOMIC>
__global__ __launch_bounds__(256, 1) void mlp_kernel(
    const float* __restrict__ x, const float* __restrict__ ea,
    const int* __restrict__ eidx, const float* __restrict__ W1,
    const float* __restrict__ b1, const float* __restrict__ lng,
    const float* __restrict__ lnb, const float* __restrict__ W2,
    const float* __restrict__ b2, float* __restrict__ out,
    unsigned short* __restrict__ h2, int E, int ntiles) {
  // 16 rows * 272B (128 bf16 + 8 pad, keeps 16B alignment, breaks bank strides)
  __shared__ __align__(16) char hbuf[4][16 * 272];
  const int tid = threadIdx.x;
  const int lane = tid & 63;
  const int wv = tid >> 6;
  const int e15 = lane & 15;
  const int q = lane >> 4;
  char* hb = hbuf[wv];

  // ---- prologue: W1/W2 as A-operand fragments, register resident ----
  // A[m][k]: m = lane&15 (+16*mt) = output feature n, k = q*8+j (+32*ks)
  bf16x8 w1f[4][8], w2f[4][8];
#pragma unroll
  for (int ks = 0; ks < 4; ++ks) {
#pragma unroll
    for (int mt = 0; mt < 8; ++mt) {
      bf16x8 a1, a2;
#pragma unroll
      for (int j = 0; j < 8; ++j) {
        int k = ks * 32 + q * 8 + j;
        int n = mt * 16 + e15;
        a1[j] = (__bf16)W1[k * 128 + n];
        a2[j] = (__bf16)W2[k * 128 + n];
      }
      w1f[ks][mt] = a1;
      w2f[ks][mt] = a2;
    }
  }
  // per-lane constants for C/D rows n = mt*16 + q*4 + r
  f32x4 b1c[8], b2c[8];
  unsigned int glc[8][4];  // low16 = bf16(ln_g), high16 = bf16(ln_b)
#pragma unroll
  for (int mt = 0; mt < 8; ++mt) {
#pragma unroll
    for (int r = 0; r < 4; ++r) {
      int n = mt * 16 + q * 4 + r;
      b1c[mt][r] = b1[n];
      b2c[mt][r] = b2[n];
      glc[mt][r] = (unsigned int)__builtin_bit_cast(unsigned short, (__bf16)lng[n]) |
                   ((unsigned int)__builtin_bit_cast(unsigned short, (__bf16)lnb[n]) << 16);
    }
  }

  const int nwav = (gridDim.x * blockDim.x) >> 6;
  const int wid = (blockIdx.x * blockDim.x + tid) >> 6;

  for (int t = wid; t < ntiles; t += nwav) {
    const int e = t * 16 + e15;
    const int row = eidx[e];
    const int cl = eidx[E + e];
    const float* xr = x + (size_t)row * 64;
    const float* ar = ea + (size_t)e * 64;
    float4 raw[4][2];
    raw[0][0] = *(const float4*)(xr + q * 8);
    raw[0][1] = *(const float4*)(xr + q * 8 + 4);
    raw[1][0] = *(const float4*)(xr + 32 + q * 8);
    raw[1][1] = *(const float4*)(xr + 32 + q * 8 + 4);
    raw[2][0] = *(const float4*)(ar + q * 8);
    raw[2][1] = *(const float4*)(ar + q * 8 + 4);
    raw[3][0] = *(const float4*)(ar + 32 + q * 8);
    raw[3][1] = *(const float4*)(ar + 32 + q * 8 + 4);
    bf16x8 bfr[4];
#pragma unroll
    for (int ks = 0; ks < 4; ++ks) {
      const float* p0 = (const float*)&raw[ks][0];
      const float* p1 = (const float*)&raw[ks][1];
#pragma unroll
      for (int j = 0; j < 4; ++j) {
        bfr[ks][j] = (__bf16)p0[j];
        bfr[ks][4 + j] = (__bf16)p1[j];
      }
    }
    f32x4 c1[8];
#pragma unroll
    for (int mt = 0; mt < 8; ++mt) c1[mt] = b1c[mt];
#pragma unroll
    for (int ks = 0; ks < 4; ++ks)
#pragma unroll
      for (int mt = 0; mt < 8; ++mt)
        c1[mt] = __builtin_amdgcn_mfma_f32_16x16x32_bf16(w1f[ks][mt], bfr[ks], c1[mt], 0, 0, 0);

    // ---- LayerNorm over 128 features of edge e (lanes e15, e15+16, +32, +48)
    float s = 0.f, ss = 0.f;
#pragma unroll
    for (int mt = 0; mt < 8; ++mt)
#pragma unroll
      for (int r = 0; r < 4; ++r) {
        float v = c1[mt][r];
        s += v;
        ss += v * v;
      }
    s += __shfl_xor(s, 16);
    s += __shfl_xor(s, 32);
    ss += __shfl_xor(ss, 16);
    ss += __shfl_xor(ss, 32);
    const float mu = s * 0.0078125f;
    const float var = ss * 0.0078125f - mu * mu;
    const float inv = rsqrtf(var + LN_EPS);
#pragma unroll
    for (int mt = 0; mt < 8; ++mt) {
      unsigned short u[4];
#pragma unroll
      for (int r = 0; r < 4; ++r) {
        float v = (c1[mt][r] - mu) * inv;
        unsigned int g = glc[mt][r];
        v = v * bflo(g) + bfhi(g);
        v = fmaxf(v, 0.f);
        u[r] = bfbits(v);
      }
      uint2 w;
      w.x = (unsigned int)u[0] | ((unsigned int)u[1] << 16);
      w.y = (unsigned int)u[2] | ((unsigned int)u[3] << 16);
      // h[e][n1], n1 = mt*16 + q*4 + r  (C-layout rows are 4-consecutive -> b64)
      *(uint2*)(hb + e15 * 272 + mt * 32 + q * 8) = w;
    }
    // ---- reload as B-operand frags: B[k][e], k = ks*32 + q*8 + j
    bf16x8 hf[4];
#pragma unroll
    for (int ks = 0; ks < 4; ++ks)
      hf[ks] = __builtin_bit_cast(bf16x8, *(const uint4*)(hb + e15 * 272 + ks * 64 + q * 16));
    f32x4 c2[8];
#pragma unroll
    for (int mt = 0; mt < 8; ++mt) c2[mt] = b2c[mt];
#pragma unroll
    for (int ks = 0; ks < 4; ++ks)
#pragma unroll
      for (int mt = 0; mt < 8; ++mt)
        c2[mt] = __builtin_amdgcn_mfma_f32_16x16x32_bf16(w2f[ks][mt], hf[ks], c2[mt], 0, 0, 0);

    if constexpr (ATOMIC) {
      float* op = out + (size_t)cl * 128 + q * 4;
#pragma unroll
      for (int mt = 0; mt < 8; ++mt)
#pragma unroll
        for (int r = 0; r < 4; ++r) unsafeAtomicAdd(op + mt * 16 + r, c2[mt][r]);
    } else {
      // stage bf16 h2 rows in LDS, then coalesced 16B stores to workspace
#pragma unroll
      for (int mt = 0; mt < 8; ++mt) {
        unsigned short u[4];
#pragma unroll
        for (int r = 0; r < 4; ++r) u[r] = bfbits(c2[mt][r]);
        uint2 w;
        w.x = (unsigned int)u[0] | ((unsigned int)u[1] << 16);
        w.y = (unsigned int)u[2] | ((unsigned int)u[3] << 16);
        *(uint2*)(hb + e15 * 272 + mt * 32 + q * 8) = w;
      }
      const int r0 = lane >> 2, c0 = lane & 3;
#pragma unroll
      for (int i = 0; i < 4; ++i) {
        uint4 v = *(const uint4*)(hb + r0 * 272 + (c0 + 4 * i) * 16);
        *(uint4*)((char*)h2 + (size_t)(t * 16 + r0) * 256 + (c0 + 4 * i) * 16) = v;
      }
    }
  }
}

// -------------------------------------------------- segmented mean (CSR path)
__global__ void reduce_kernel(const unsigned short* __restrict__ h2,
                              const int* __restrict__ off, const int* __restrict__ cnt,
                              const int* __restrict__ perm, float* __restrict__ out, int N) {
  int tid = blockIdx.x * blockDim.x + threadIdx.x;
  int node = tid >> 4;  // 16 lanes per node, 8 features each
  if (node >= N) return;
  int sub = tid & 15;
  int deg = cnt[node];
  int start = off[node];
  float acc[8] = {0.f, 0.f, 0.f, 0.f, 0.f, 0.f, 0.f, 0.f};
  for (int j = 0; j < deg; ++j) {
    int e = perm[start + j];
    uint4 v = *(const uint4*)(h2 + (size_t)e * 128 + sub * 8);
    acc[0] += bflo(v.x);
    acc[1] += bfhi(v.x);
    acc[2] += bflo(v.y);
    acc[3] += bfhi(v.y);
    acc[4] += bflo(v.z);
    acc[5] += bfhi(v.z);
    acc[6] += bflo(v.w);
    acc[7] += bfhi(v.w);
  }
  float sc = 1.f / (float)(deg > 0 ? deg : 1);
  float* op = out + (size_t)node * 128 + sub * 8;
  float4 o;
  o.x = acc[0] * sc;
  o.y = acc[1] * sc;
  o.z = acc[2] * sc;
  o.w = acc[3] * sc;
  *(float4*)op = o;
  o.x = acc[4] * sc;
  o.y = acc[5] * sc;
  o.z = acc[6] * sc;
  o.w = acc[7] * sc;
  *(float4*)(op + 4) = o;
}

// ------------------------------------------------------ divide (atomic path)
__global__ void divide_kernel(float* __restrict__ out, const int* __restrict__ cnt, int N) {
  int i = blockIdx.x * blockDim.x + threadIdx.x;
  if (i >= N * 32) return;  // N*128/4 float4s
  int node = i >> 5;
  float s = 1.f / (float)(cnt[node] > 0 ? cnt[node] : 1);
  float4* p = (float4*)out + i;
  float4 v = *p;
  v.x *= s;
  v.y *= s;
  v.z *= s;
  v.w *= s;
  *p = v;
}

extern "C" void kernel_launch(void* const* d_in, const int* in_sizes, int n_in,
                              void* d_out, int out_size, void* d_ws, size_t ws_size,
                              hipStream_t stream) {
  const float* x = (const float*)d_in[0];
  const float* ea = (const float*)d_in[1];
  const int* eidx = (const int*)d_in[2];
  const float* W1 = (const float*)d_in[3];
  const float* b1 = (const float*)d_in[4];
  const float* lng = (const float*)d_in[5];
  const float* lnb = (const float*)d_in[6];
  const float* W2 = (const float*)d_in[7];
  const float* b2 = (const float*)d_in[8];
  float* out = (float*)d_out;

  const int N = in_sizes[0] / 64;   // 50000
  const int E = in_sizes[1] / 64;   // 800000
  const int ntiles = E / 16;
  const size_t h2B = (size_t)E * 256;   // bf16 h2 rows
  const size_t permB = (size_t)E * 4;
  const size_t cB = (size_t)N * 4;
  const size_t need = h2B + permB + 3 * cB;
  const int eblocks = (E + 255) / 256;

  if (ws_size >= need) {
    // ---- two-phase CSR path: no fp32 atomic storm ----
    unsigned short* h2 = (unsigned short*)d_ws;
    char* base = (char*)d_ws + h2B;
    int* perm = (int*)base;
    int* cnt = (int*)(base + permB);
    int* cur = (int*)(base + permB + cB);
    int* off = (int*)(base + permB + 2 * cB);
    hipMemsetAsync(cnt, 0, 2 * cB, stream);  // cnt + cur contiguous
    hist_kernel<<<eblocks, 256, 0, stream>>>(eidx, cnt, E);
    scan_kernel<<<1, 1024, 0, stream>>>(cnt, off, N);
    scatter_kernel<<<eblocks, 256, 0, stream>>>(eidx, off, cur, perm, E);
    mlp_kernel<false><<<256, 256, 0, stream>>>(x, ea, eidx, W1, b1, lng, lnb, W2, b2,
                                               out, h2, E, ntiles);
    reduce_kernel<<<(N * 16 + 255) / 256, 256, 0, stream>>>(h2, off, cnt, perm, out, N);
  } else {
    // ---- fallback: fused atomic scatter (needs only N*4 bytes of ws) ----
    int* cnt = (int*)d_ws;
    hipMemsetAsync(out, 0, (size_t)out_size * 4, stream);
    hipMemsetAsync(cnt, 0, cB, stream);
    hist_kernel<<<eblocks, 256, 0, stream>>>(eidx, cnt, E);
    mlp_kernel<true><<<256, 256, 0, stream>>>(x, ea, eidx, W1, b1, lng, lnb, W2, b2,
                                              out, (unsigned short*)d_ws, E, ntiles);
    divide_kernel<<<(N * 32 + 255) / 256, 256, 0, stream>>>(out, cnt, N);
  }
}